// Round 3
// 934.476 us; speedup vs baseline: 1.0398x; 1.0398x over previous
//
#include <hip/hip_runtime.h>
#include <stdint.h>

typedef __attribute__((ext_vector_type(8))) short short8;
typedef __attribute__((ext_vector_type(8))) unsigned short ushort8;
typedef __attribute__((ext_vector_type(4))) unsigned short bf16x4;
typedef __attribute__((ext_vector_type(4))) float float4_t;

#define AS1 __attribute__((address_space(1)))
#define AS3 __attribute__((address_space(3)))

// round-to-nearest-even fp32 -> bf16 (branch-free)
__device__ __forceinline__ unsigned short f2bf(float f) {
    union { float f; unsigned u; } c; c.f = f;
    return (unsigned short)((c.u + 0x7fffu + ((c.u >> 16) & 1u)) >> 16);
}

// async global->LDS, 16B per lane. LDS dest must be wave-uniform base + lane*16.
__device__ __forceinline__ void load16_lds(const void* g, void* l) {
    __builtin_amdgcn_global_load_lds((const AS1 void*)(uintptr_t)g,
                                     (AS3 void*)(uintptr_t)l, 16, 0, 0);
}

// drain global_load_lds queue, then block barrier; memory clobbers pin code motion
__device__ __forceinline__ void wait_vm0_barrier() {
    asm volatile("s_waitcnt vmcnt(0)" ::: "memory");
    __builtin_amdgcn_s_barrier();
    asm volatile("" ::: "memory");
}

// ---------------------------------------------------------------------------
// fp32 -> bf16 convert, 8 elems/thread
__global__ __launch_bounds__(256)
void cvt_x(const float4_t* __restrict__ x, unsigned short* __restrict__ xb, int n8) {
    int i = blockIdx.x * 256 + threadIdx.x;
    if (i >= n8) return;
    float4_t a = x[2 * i], b = x[2 * i + 1];
    ushort8 v;
    v[0] = f2bf(a[0]); v[1] = f2bf(a[1]); v[2] = f2bf(a[2]); v[3] = f2bf(a[3]);
    v[4] = f2bf(b[0]); v[5] = f2bf(b[1]); v[6] = f2bf(b[2]); v[7] = f2bf(b[3]);
    ((ushort8*)xb)[i] = v;
}

// ---------------------------------------------------------------------------
// prep: weight transpose+convert (B^T layout), padded bias/mask tables.
// biasP: (16, 49, 64) fp32, n>=49 -> 0
// maskP: (64, 49, 64) fp32, n>=49 -> -1e30 (kills padded cols in softmax)
__global__ __launch_bounds__(256)
void prep(const float* __restrict__ qkv_w, const float* __restrict__ proj_w,
          const float* __restrict__ bias_tab, const int* __restrict__ rel_idx,
          const float* __restrict__ mask,
          unsigned short* __restrict__ qkv_wT, unsigned short* __restrict__ proj_wT,
          float* __restrict__ biasP, float* __restrict__ maskP) {
    int i = blockIdx.x * 256 + threadIdx.x;
    if (i < 786432) {                       // qkv_wT[n][k], n<1536,k<512
        int n = i >> 9, k = i & 511;
        qkv_wT[i] = f2bf(qkv_w[k * 1536 + n]);
    } else if (i < 1048576) {               // proj_wT[n][k], n<512,k<512
        int j = i - 786432;
        int n = j >> 9, k = j & 511;
        proj_wT[j] = f2bf(proj_w[k * 512 + n]);
    } else if (i < 1098752) {               // biasP: 16*3136
        int j = i - 1048576;
        int h = j / 3136, mn = j % 3136;
        int m = mn >> 6, n = mn & 63;
        biasP[j] = (n < 49) ? bias_tab[rel_idx[m * 49 + n] * 16 + h] : 0.0f;
    } else {                                // maskP: 64*3136, ends exactly at 1299456
        int j = i - 1098752;
        int w = j / 3136, mn = j % 3136;
        int m = mn >> 6, n = mn & 63;
        maskP[j] = (n < 49) ? mask[w * 2401 + m * 49 + n] : -1e30f;
    }
}

// ---------------------------------------------------------------------------
// bf16 GEMM: C(MxN) = A(MxK) * B^T  (B stored N x K row-major)
// 128x128 tile, BK=32, 4 waves (2x2 of 64x64), 16x16x32 bf16 MFMA.
// Double-buffered LDS: stage tile k+1 while computing tile k; single raw
// barrier + vmcnt(0) per iter (loads in flight during MFMA).
// Swapped-operand MFMA: lane holds 4 consecutive columns -> vectorized stores.
// 1-D grid with XCD-chunked swizzle (gridDim.x % 8 == 0).
// MODE 0: bf16 out, fp32 bias, cols<512 scaled by qscale (QKV epilogue)
// MODE 1: fp32 out + bias (proj epilogue)
template <int MODE>
__global__ __launch_bounds__(256)
void gemm_bt(const unsigned short* __restrict__ A, const unsigned short* __restrict__ B,
             void* __restrict__ Cv, const float* __restrict__ bias,
             int M, int N, int K, float qscale) {
    __shared__ __align__(16) unsigned short As[2][128 * 32];
    __shared__ __align__(16) unsigned short Bs[2][128 * 32];

    const int t = threadIdx.x;
    const int lane = t & 63;
    const int wave = t >> 6;
    const int col = lane & 15;
    const int quad = lane >> 4;
    const int wm = (wave & 1) * 64;
    const int wn = (wave >> 1) * 64;

    // XCD-chunked swizzle: XCD c gets contiguous work chunk [c*cpx, (c+1)*cpx).
    const int nwg = gridDim.x;
    const int cpx = nwg >> 3;
    const int wg = (blockIdx.x & 7) * cpx + (blockIdx.x >> 3);
    const int nbx = N >> 7;
    const int m0 = (wg / nbx) * 128;
    const int n0 = (wg % nbx) * 128;

    float4_t acc[4][4] = {};

    const int row = t >> 2;   // 0..63 (two issues cover 128 rows)
    const int seg = t & 3;    // 16B segment within a 64B row
    const unsigned short* Ag0 = A + (size_t)(m0 + row) * K + seg * 8;
    const unsigned short* Ag1 = A + (size_t)(m0 + 64 + row) * K + seg * 8;
    const unsigned short* Bg0 = B + (size_t)(n0 + row) * K + seg * 8;
    const unsigned short* Bg1 = B + (size_t)(n0 + 64 + row) * K + seg * 8;

    // prologue: stage tile 0 into buf 0
    load16_lds(Ag0, &As[0][t * 8]);
    load16_lds(Ag1, &As[0][2048 + t * 8]);
    load16_lds(Bg0, &Bs[0][t * 8]);
    load16_lds(Bg1, &Bs[0][2048 + t * 8]);
    wait_vm0_barrier();

    int cur = 0;
    for (int kk = 0; kk < K; kk += 32) {
        if (kk + 32 < K) {                 // stage next tile into other buffer
            int nb = cur ^ 1;
            load16_lds(Ag0 + kk + 32, &As[nb][t * 8]);
            load16_lds(Ag1 + kk + 32, &As[nb][2048 + t * 8]);
            load16_lds(Bg0 + kk + 32, &Bs[nb][t * 8]);
            load16_lds(Bg1 + kk + 32, &Bs[nb][2048 + t * 8]);
        }
        short8 a[4], b[4];
#pragma unroll
        for (int i = 0; i < 4; ++i)
            a[i] = *(const short8*)&As[cur][(wm + i * 16 + col) * 32 + quad * 8];
#pragma unroll
        for (int j = 0; j < 4; ++j)
            b[j] = *(const short8*)&Bs[cur][(wn + j * 16 + col) * 32 + quad * 8];
#pragma unroll
        for (int i = 0; i < 4; ++i)
#pragma unroll
            for (int j = 0; j < 4; ++j)  // swapped operands: p-dim = B-rows (n)
                acc[i][j] = __builtin_amdgcn_mfma_f32_16x16x32_bf16(b[j], a[i], acc[i][j], 0, 0, 0);

        wait_vm0_barrier();                // next-tile loads had MFMA time to land
        cur ^= 1;
    }

    // Swapped layout: acc[i][j][r] = C[m0+wm+i*16+col][n0+wn+j*16+quad*4+r]
    if (MODE == 0) {
        unsigned short* C = (unsigned short*)Cv;
#pragma unroll
        for (int j = 0; j < 4; ++j) {
            int gc0 = n0 + wn + j * 16 + quad * 4;
            float4_t bv = *(const float4_t*)&bias[gc0];
            float sc = (gc0 < 512) ? qscale : 1.0f;   // q section gets d^-0.5
#pragma unroll
            for (int i = 0; i < 4; ++i) {
                int gr = m0 + wm + i * 16 + col;
                bf16x4 u;
#pragma unroll
                for (int r = 0; r < 4; ++r) u[r] = f2bf((acc[i][j][r] + bv[r]) * sc);
                *(bf16x4*)&C[(size_t)gr * N + gc0] = u;
            }
        }
    } else {
        float* C = (float*)Cv;
#pragma unroll
        for (int j = 0; j < 4; ++j) {
            int gc0 = n0 + wn + j * 16 + quad * 4;
            float4_t bv = *(const float4_t*)&bias[gc0];
#pragma unroll
            for (int i = 0; i < 4; ++i) {
                int gr = m0 + wm + i * 16 + col;
                float4_t ov = acc[i][j] + bv;
                *(float4_t*)&C[(size_t)gr * N + gc0] = ov;
            }
        }
    }
}

// ---------------------------------------------------------------------------
// window attention: one wave per (window, head). 49 padded to 64.
// Swapped QK^T: S^T fragments -> softmax row is 16 lane-local vals + 2 shfl.
// P/Vt in LDS with XOR row swizzle (conflict-free b128 reads).
// qkv layout: (100352,1536) bf16, cols [0,512)=q (pre-scaled), [512,1024)=k, [1024,1536)=v
__global__ __launch_bounds__(64)
void attn_win(const unsigned short* __restrict__ qkv,
              const float* __restrict__ maskP,    // (64,49,64) fp32, padded
              const float* __restrict__ biasP,    // (16,49,64) fp32, padded
              unsigned short* __restrict__ attn_out) {  // (100352,512) bf16
    __shared__ __align__(16) unsigned short P[64 * 64];   // probs, row-major, swizzled
    __shared__ __align__(16) unsigned short Vt[32 * 64];  // V^T: [d][token], swizzled

    const int bh = blockIdx.x;
    const int w = bh >> 4;
    const int hh = bh & 15;
    const int lane = threadIdx.x;
    const int col = lane & 15;
    const int quad = lane >> 4;
    const size_t rowbase = (size_t)(w * 49) * 1536;

    // ---- stage V^T (tokens >=49 zero), rows XOR-swizzled ----
    {
        ushort8 u0 = {}, u1 = {}, u2 = {}, u3 = {};
        if (lane < 49) {
            const ushort8* vp = (const ushort8*)(qkv + rowbase + (size_t)lane * 1536 + 1024 + hh * 32);
            u0 = vp[0]; u1 = vp[1]; u2 = vp[2]; u3 = vp[3];
        }
#pragma unroll
        for (int c = 0; c < 8; ++c) {
            Vt[((c) * 64 + lane) ^ ((c & 7) << 3)] = u0[c];
            Vt[((c + 8) * 64 + lane) ^ ((c & 7) << 3)] = u1[c];
            Vt[((c + 16) * 64 + lane) ^ ((c & 7) << 3)] = u2[c];
            Vt[((c + 24) * 64 + lane) ^ ((c & 7) << 3)] = u3[c];
        }
    }

    // ---- S^T = (K)(Q) via swapped MFMA: s[i][j][r] = S[m=i*16+col][n=j*16+quad*4+r]
    float4_t s[4][4] = {};
    {
        short8 qf[4], kf[4];
#pragma unroll
        for (int i = 0; i < 4; ++i) {
            int m = i * 16 + col; if (m > 48) m = 48;   // clamp: rows/cols >=49 masked later
            qf[i] = *(const short8*)(qkv + rowbase + (size_t)m * 1536 + hh * 32 + quad * 8);
            kf[i] = *(const short8*)(qkv + rowbase + (size_t)m * 1536 + 512 + hh * 32 + quad * 8);
        }
#pragma unroll
        for (int i = 0; i < 4; ++i)
#pragma unroll
            for (int j = 0; j < 4; ++j)
                s[i][j] = __builtin_amdgcn_mfma_f32_16x16x32_bf16(kf[j], qf[i], s[i][j], 0, 0, 0);
    }

    // ---- + rel-pos bias + shift mask (padded tables; n>=49 gets -1e30) ----
    {
        const float* mk = maskP + (size_t)(w & 63) * 3136;
        const float* bs = biasP + (size_t)hh * 3136;
#pragma unroll
        for (int i = 0; i < 4; ++i) {
            int mc = i * 16 + col; if (mc > 48) mc = 48;
#pragma unroll
            for (int j = 0; j < 4; ++j) {
                int n0 = j * 16 + quad * 4;
                float4_t a4 = *(const float4_t*)&mk[mc * 64 + n0];
                float4_t b4 = *(const float4_t*)&bs[mc * 64 + n0];
#pragma unroll
                for (int r = 0; r < 4; ++r) s[i][j][r] += a4[r] + b4[r];
            }
        }
    }

    // ---- softmax per row m: 16 lane-local values + cross-quad shfl(16,32) ----
#pragma unroll
    for (int i = 0; i < 4; ++i) {
        int m = i * 16 + col;
        float mx = s[i][0][0];
#pragma unroll
        for (int j = 0; j < 4; ++j)
#pragma unroll
            for (int r = 0; r < 4; ++r) mx = fmaxf(mx, s[i][j][r]);
        mx = fmaxf(mx, __shfl_xor(mx, 16));
        mx = fmaxf(mx, __shfl_xor(mx, 32));
        float sum = 0.f;
#pragma unroll
        for (int j = 0; j < 4; ++j)
#pragma unroll
            for (int r = 0; r < 4; ++r) {
                float e = __expf(s[i][j][r] - mx);
                s[i][j][r] = e; sum += e;
            }
        sum += __shfl_xor(sum, 16);
        sum += __shfl_xor(sum, 32);
        float inv = 1.0f / sum;
#pragma unroll
        for (int j = 0; j < 4; ++j) {
            bf16x4 u;
#pragma unroll
            for (int r = 0; r < 4; ++r) u[r] = f2bf(s[i][j][r] * inv);
            *(bf16x4*)&P[(m * 64 + j * 16 + quad * 4) ^ ((m & 7) << 3)] = u;
        }
    }
    __syncthreads();

    // ---- O^T = (V^T)(P) via swapped MFMA: o[i][tj][r] = O[m=i*16+col][d=tj*16+quad*4+r]
    float4_t o[4][2] = {};
#pragma unroll
    for (int s2 = 0; s2 < 2; ++s2) {
        short8 pa[4], vb[2];
#pragma unroll
        for (int i = 0; i < 4; ++i) {
            int m = i * 16 + col;
            pa[i] = *(const short8*)&P[(m * 64 + s2 * 32 + quad * 8) ^ ((m & 7) << 3)];
        }
#pragma unroll
        for (int tj = 0; tj < 2; ++tj) {
            int d = tj * 16 + col;
            vb[tj] = *(const short8*)&Vt[(d * 64 + s2 * 32 + quad * 8) ^ ((d & 7) << 3)];
        }
#pragma unroll
        for (int i = 0; i < 4; ++i)
#pragma unroll
            for (int tj = 0; tj < 2; ++tj)
                o[i][tj] = __builtin_amdgcn_mfma_f32_16x16x32_bf16(vb[tj], pa[i], o[i][tj], 0, 0, 0);
    }

    // ---- store (bf16, (M,512) row-major feeds proj GEMM), bf16x4 vectorized ----
#pragma unroll
    for (int i = 0; i < 4; ++i) {
        int m = i * 16 + col;
        if (m < 49) {
            size_t ob = (size_t)(w * 49 + m) * 512 + hh * 32 + quad * 4;
#pragma unroll
            for (int tj = 0; tj < 2; ++tj) {
                bf16x4 u;
#pragma unroll
                for (int r = 0; r < 4; ++r) u[r] = f2bf(o[i][tj][r]);
                *(bf16x4*)&attn_out[ob + tj * 16] = u;
            }
        }
    }
}

// ---------------------------------------------------------------------------
extern "C" void kernel_launch(void* const* d_in, const int* in_sizes, int n_in,
                              void* d_out, int out_size, void* d_ws, size_t ws_size,
                              hipStream_t stream) {
    const float* x        = (const float*)d_in[0];
    const float* mask     = (const float*)d_in[1];
    const float* qkv_w    = (const float*)d_in[2];
    const float* qkv_b    = (const float*)d_in[3];
    const float* proj_w   = (const float*)d_in[4];
    const float* proj_b   = (const float*)d_in[5];
    const float* bias_tab = (const float*)d_in[6];
    const int*   rel_idx  = (const int*)d_in[7];
    float* out = (float*)d_out;

    char* ws = (char*)d_ws;
    size_t off = 0;
    auto carve = [&](size_t bytes) -> char* {
        char* p = ws + off;
        off += (bytes + 255) & ~(size_t)255;
        return p;
    };
    unsigned short* x_bf    = (unsigned short*)carve((size_t)51380224 * 2);   // 102.8 MB
    unsigned short* qkv_wT  = (unsigned short*)carve((size_t)786432 * 2);
    unsigned short* proj_wT = (unsigned short*)carve((size_t)262144 * 2);
    float*          biasP   = (float*)carve((size_t)50176 * 4);
    float*          maskP   = (float*)carve((size_t)200704 * 4);
    unsigned short* qkv_o   = (unsigned short*)carve((size_t)100352 * 1536 * 2); // 308.3 MB
    unsigned short* attn_o  = x_bf;  // x_bf dead after QKV GEMM; alias saves 103 MB

    cvt_x<<<25088, 256, 0, stream>>>((const float4_t*)x, x_bf, 6422528);
    prep<<<5076, 256, 0, stream>>>(qkv_w, proj_w, bias_tab, rel_idx, mask,
                                   qkv_wT, proj_wT, biasP, maskP);
    // qkv = x @ qkv_w + b, q-cols scaled by 32^-0.5, bf16 out
    gemm_bt<0><<<9408, 256, 0, stream>>>(x_bf, qkv_wT, (void*)qkv_o, qkv_b,
                                         100352, 1536, 512, 0.17677669529663687f);
    attn_win<<<32768, 64, 0, stream>>>(qkv_o, maskP, biasP, attn_o);
    // out = attn_o @ proj_w + proj_b, fp32 out
    gemm_bt<1><<<3136, 256, 0, stream>>>(attn_o, proj_wT, (void*)out, proj_b,
                                         100352, 512, 512, 1.0f);
}

// Round 4
// 916.660 us; speedup vs baseline: 1.0601x; 1.0194x over previous
//
#include <hip/hip_runtime.h>
#include <stdint.h>

typedef __attribute__((ext_vector_type(8))) short short8;
typedef __attribute__((ext_vector_type(8))) unsigned short ushort8;
typedef __attribute__((ext_vector_type(4))) unsigned short bf16x4;
typedef __attribute__((ext_vector_type(4))) float float4_t;

#define AS1 __attribute__((address_space(1)))
#define AS3 __attribute__((address_space(3)))

// round-to-nearest-even fp32 -> bf16 (branch-free)
__device__ __forceinline__ unsigned short f2bf(float f) {
    union { float f; unsigned u; } c; c.f = f;
    return (unsigned short)((c.u + 0x7fffu + ((c.u >> 16) & 1u)) >> 16);
}

// async global->LDS, 16B per lane. LDS dest must be wave-uniform base + lane*16.
__device__ __forceinline__ void load16_lds(const void* g, void* l) {
    __builtin_amdgcn_global_load_lds((const AS1 void*)(uintptr_t)g,
                                     (AS3 void*)(uintptr_t)l, 16, 0, 0);
}

// ---------------------------------------------------------------------------
// fp32 -> bf16 convert, 8 elems/thread
__global__ __launch_bounds__(256)
void cvt_x(const float4_t* __restrict__ x, unsigned short* __restrict__ xb, int n8) {
    int i = blockIdx.x * 256 + threadIdx.x;
    if (i >= n8) return;
    float4_t a = x[2 * i], b = x[2 * i + 1];
    ushort8 v;
    v[0] = f2bf(a[0]); v[1] = f2bf(a[1]); v[2] = f2bf(a[2]); v[3] = f2bf(a[3]);
    v[4] = f2bf(b[0]); v[5] = f2bf(b[1]); v[6] = f2bf(b[2]); v[7] = f2bf(b[3]);
    ((ushort8*)xb)[i] = v;
}

// ---------------------------------------------------------------------------
// prep: weight transpose+convert (B^T layout), padded bias/mask tables.
// biasP: (16, 49, 64) fp32, n>=49 -> 0
// maskP: (64, 49, 64) fp32, n>=49 -> -1e30 (kills padded cols in softmax)
__global__ __launch_bounds__(256)
void prep(const float* __restrict__ qkv_w, const float* __restrict__ proj_w,
          const float* __restrict__ bias_tab, const int* __restrict__ rel_idx,
          const float* __restrict__ mask,
          unsigned short* __restrict__ qkv_wT, unsigned short* __restrict__ proj_wT,
          float* __restrict__ biasP, float* __restrict__ maskP) {
    int i = blockIdx.x * 256 + threadIdx.x;
    if (i < 786432) {                       // qkv_wT[n][k], n<1536,k<512
        int n = i >> 9, k = i & 511;
        qkv_wT[i] = f2bf(qkv_w[k * 1536 + n]);
    } else if (i < 1048576) {               // proj_wT[n][k], n<512,k<512
        int j = i - 786432;
        int n = j >> 9, k = j & 511;
        proj_wT[j] = f2bf(proj_w[k * 512 + n]);
    } else if (i < 1098752) {               // biasP: 16*3136
        int j = i - 1048576;
        int h = j / 3136, mn = j % 3136;
        int m = mn >> 6, n = mn & 63;
        biasP[j] = (n < 49) ? bias_tab[rel_idx[m * 49 + n] * 16 + h] : 0.0f;
    } else {                                // maskP: 64*3136, ends exactly at 1299456
        int j = i - 1098752;
        int w = j / 3136, mn = j % 3136;
        int m = mn >> 6, n = mn & 63;
        maskP[j] = (n < 49) ? mask[w * 2401 + m * 49 + n] : -1e30f;
    }
}

// ---------------------------------------------------------------------------
// bf16 GEMM: C(MxN) = A(MxK) * B^T  (B stored N x K row-major)
// 128x128 tile, BK=32, 4 waves (2x2 of 64x64), 16x16x32 bf16 MFMA.
// Depth-3 pipeline: 4 LDS buffers, counted vmcnt (T4) so each tile's loads
// get ~2.5 compute phases to land; single barrier per K-step.
//   prologue: stage tiles 0,1,2
//   iter t:   vmcnt(8) [tile t landed; t+1,t+2 in flight] ; barrier ;
//             stage tile t+3 into buf[(t+3)&3] ; ds_read buf[t&3] ; MFMA
// WAR-safe: stage(t+3) overwrites buf[(t-1)&3]; all waves passed barrier(t),
// so iter t-1's readers are done. Requires nt = K/32 >= 3 (K=512 here).
// MODE 0: bf16 out, fp32 bias, cols<512 scaled by qscale (QKV epilogue)
// MODE 1: fp32 out + bias (proj epilogue)
template <int MODE>
__global__ __launch_bounds__(256)
void gemm_bt(const unsigned short* __restrict__ A, const unsigned short* __restrict__ B,
             void* __restrict__ Cv, const float* __restrict__ bias,
             int M, int N, int K, float qscale) {
    __shared__ __align__(16) unsigned short As[4 * 128 * 32];   // 32 KB
    __shared__ __align__(16) unsigned short Bs[4 * 128 * 32];   // 32 KB

    const int t = threadIdx.x;
    const int lane = t & 63;
    const int wave = t >> 6;
    const int col = lane & 15;
    const int quad = lane >> 4;
    const int wm = (wave & 1) * 64;
    const int wn = (wave >> 1) * 64;

    // XCD-chunked swizzle: XCD c gets contiguous work chunk [c*cpx, (c+1)*cpx).
    const int nwg = gridDim.x;
    const int cpx = nwg >> 3;
    const int wg = (blockIdx.x & 7) * cpx + (blockIdx.x >> 3);
    const int nbx = N >> 7;
    const int m0 = (wg / nbx) * 128;
    const int n0 = (wg % nbx) * 128;

    float4_t acc[4][4] = {};

    const int row = t >> 2;   // 0..63 (two issues cover 128 rows)
    const int seg = t & 3;    // 16B segment within a 64B row
    const unsigned short* Ag0 = A + (size_t)(m0 + row) * K + seg * 8;
    const unsigned short* Ag1 = A + (size_t)(m0 + 64 + row) * K + seg * 8;
    const unsigned short* Bg0 = B + (size_t)(n0 + row) * K + seg * 8;
    const unsigned short* Bg1 = B + (size_t)(n0 + 64 + row) * K + seg * 8;

    // stage tile -> buf[tile&3]; 4 vmcnt ops per call per wave
    auto stage = [&](int tile) {
        const int kk = tile << 5;
        unsigned short* Ad = As + ((tile & 3) << 12);
        unsigned short* Bd = Bs + ((tile & 3) << 12);
        load16_lds(Ag0 + kk, Ad + t * 8);
        load16_lds(Ag1 + kk, Ad + 2048 + t * 8);
        load16_lds(Bg0 + kk, Bd + t * 8);
        load16_lds(Bg1 + kk, Bd + 2048 + t * 8);
    };

    const int nt = K >> 5;            // # K-tiles (nt >= 3 assumed)
    stage(0); stage(1); stage(2);     // 12 loads in flight

    for (int tt = 0; tt < nt; ++tt) {
        // counted wait: tile tt complete; up to 2 younger tiles (8 ops) in flight
        if (tt < nt - 2)       asm volatile("s_waitcnt vmcnt(8)" ::: "memory");
        else if (tt == nt - 2) asm volatile("s_waitcnt vmcnt(4)" ::: "memory");
        else                   asm volatile("s_waitcnt vmcnt(0)" ::: "memory");
        __builtin_amdgcn_s_barrier();
        asm volatile("" ::: "memory");

        if (tt + 3 < nt) stage(tt + 3);   // issue-early: lands by iter tt+3

        const unsigned short* Ab = As + ((size_t)(tt & 3) << 12);
        const unsigned short* Bb = Bs + ((size_t)(tt & 3) << 12);
        short8 a[4], b[4];
#pragma unroll
        for (int i = 0; i < 4; ++i)
            a[i] = *(const short8*)&Ab[(wm + i * 16 + col) * 32 + quad * 8];
#pragma unroll
        for (int j = 0; j < 4; ++j)
            b[j] = *(const short8*)&Bb[(wn + j * 16 + col) * 32 + quad * 8];
        __builtin_amdgcn_s_setprio(1);
#pragma unroll
        for (int i = 0; i < 4; ++i)
#pragma unroll
            for (int j = 0; j < 4; ++j)  // swapped operands: p-dim = B-rows (n)
                acc[i][j] = __builtin_amdgcn_mfma_f32_16x16x32_bf16(b[j], a[i], acc[i][j], 0, 0, 0);
        __builtin_amdgcn_s_setprio(0);
    }

    // Swapped layout: acc[i][j][r] = C[m0+wm+i*16+col][n0+wn+j*16+quad*4+r]
    if (MODE == 0) {
        unsigned short* C = (unsigned short*)Cv;
#pragma unroll
        for (int j = 0; j < 4; ++j) {
            int gc0 = n0 + wn + j * 16 + quad * 4;
            float4_t bv = *(const float4_t*)&bias[gc0];
            float sc = (gc0 < 512) ? qscale : 1.0f;   // q section gets d^-0.5
#pragma unroll
            for (int i = 0; i < 4; ++i) {
                int gr = m0 + wm + i * 16 + col;
                bf16x4 u;
#pragma unroll
                for (int r = 0; r < 4; ++r) u[r] = f2bf((acc[i][j][r] + bv[r]) * sc);
                *(bf16x4*)&C[(size_t)gr * N + gc0] = u;
            }
        }
    } else {
        float* C = (float*)Cv;
#pragma unroll
        for (int j = 0; j < 4; ++j) {
            int gc0 = n0 + wn + j * 16 + quad * 4;
            float4_t bv = *(const float4_t*)&bias[gc0];
#pragma unroll
            for (int i = 0; i < 4; ++i) {
                int gr = m0 + wm + i * 16 + col;
                float4_t ov = acc[i][j] + bv;
                *(float4_t*)&C[(size_t)gr * N + gc0] = ov;
            }
        }
    }
}

// ---------------------------------------------------------------------------
// window attention: one wave per (window, head). 49 padded to 64.
// Swapped QK^T: S^T fragments -> softmax row is 16 lane-local vals + 2 shfl.
// P/Vt in LDS with XOR row swizzle (conflict-free b128 reads).
// qkv layout: (100352,1536) bf16, cols [0,512)=q (pre-scaled), [512,1024)=k, [1024,1536)=v
__global__ __launch_bounds__(64)
void attn_win(const unsigned short* __restrict__ qkv,
              const float* __restrict__ maskP,    // (64,49,64) fp32, padded
              const float* __restrict__ biasP,    // (16,49,64) fp32, padded
              unsigned short* __restrict__ attn_out) {  // (100352,512) bf16
    __shared__ __align__(16) unsigned short P[64 * 64];   // probs, row-major, swizzled
    __shared__ __align__(16) unsigned short Vt[32 * 64];  // V^T: [d][token], swizzled

    const int bh = blockIdx.x;
    const int w = bh >> 4;
    const int hh = bh & 15;
    const int lane = threadIdx.x;
    const int col = lane & 15;
    const int quad = lane >> 4;
    const size_t rowbase = (size_t)(w * 49) * 1536;

    // ---- stage V^T (tokens >=49 zero), rows XOR-swizzled ----
    {
        ushort8 u0 = {}, u1 = {}, u2 = {}, u3 = {};
        if (lane < 49) {
            const ushort8* vp = (const ushort8*)(qkv + rowbase + (size_t)lane * 1536 + 1024 + hh * 32);
            u0 = vp[0]; u1 = vp[1]; u2 = vp[2]; u3 = vp[3];
        }
#pragma unroll
        for (int c = 0; c < 8; ++c) {
            Vt[((c) * 64 + lane) ^ ((c & 7) << 3)] = u0[c];
            Vt[((c + 8) * 64 + lane) ^ ((c & 7) << 3)] = u1[c];
            Vt[((c + 16) * 64 + lane) ^ ((c & 7) << 3)] = u2[c];
            Vt[((c + 24) * 64 + lane) ^ ((c & 7) << 3)] = u3[c];
        }
    }

    // ---- S^T = (K)(Q) via swapped MFMA: s[i][j][r] = S[m=i*16+col][n=j*16+quad*4+r]
    float4_t s[4][4] = {};
    {
        short8 qf[4], kf[4];
#pragma unroll
        for (int i = 0; i < 4; ++i) {
            int m = i * 16 + col; if (m > 48) m = 48;   // clamp: rows/cols >=49 masked later
            qf[i] = *(const short8*)(qkv + rowbase + (size_t)m * 1536 + hh * 32 + quad * 8);
            kf[i] = *(const short8*)(qkv + rowbase + (size_t)m * 1536 + 512 + hh * 32 + quad * 8);
        }
        __builtin_amdgcn_s_setprio(1);
#pragma unroll
        for (int i = 0; i < 4; ++i)
#pragma unroll
            for (int j = 0; j < 4; ++j)
                s[i][j] = __builtin_amdgcn_mfma_f32_16x16x32_bf16(kf[j], qf[i], s[i][j], 0, 0, 0);
        __builtin_amdgcn_s_setprio(0);
    }

    // ---- + rel-pos bias + shift mask (padded tables; n>=49 gets -1e30) ----
    {
        const float* mk = maskP + (size_t)(w & 63) * 3136;
        const float* bs = biasP + (size_t)hh * 3136;
#pragma unroll
        for (int i = 0; i < 4; ++i) {
            int mc = i * 16 + col; if (mc > 48) mc = 48;
#pragma unroll
            for (int j = 0; j < 4; ++j) {
                int n0 = j * 16 + quad * 4;
                float4_t a4 = *(const float4_t*)&mk[mc * 64 + n0];
                float4_t b4 = *(const float4_t*)&bs[mc * 64 + n0];
#pragma unroll
                for (int r = 0; r < 4; ++r) s[i][j][r] += a4[r] + b4[r];
            }
        }
    }

    // ---- softmax per row m: 16 lane-local values + cross-quad shfl(16,32) ----
#pragma unroll
    for (int i = 0; i < 4; ++i) {
        int m = i * 16 + col;
        float mx = s[i][0][0];
#pragma unroll
        for (int j = 0; j < 4; ++j)
#pragma unroll
            for (int r = 0; r < 4; ++r) mx = fmaxf(mx, s[i][j][r]);
        mx = fmaxf(mx, __shfl_xor(mx, 16));
        mx = fmaxf(mx, __shfl_xor(mx, 32));
        float sum = 0.f;
#pragma unroll
        for (int j = 0; j < 4; ++j)
#pragma unroll
            for (int r = 0; r < 4; ++r) {
                float e = __expf(s[i][j][r] - mx);
                s[i][j][r] = e; sum += e;
            }
        sum += __shfl_xor(sum, 16);
        sum += __shfl_xor(sum, 32);
        float inv = 1.0f / sum;
#pragma unroll
        for (int j = 0; j < 4; ++j) {
            bf16x4 u;
#pragma unroll
            for (int r = 0; r < 4; ++r) u[r] = f2bf(s[i][j][r] * inv);
            *(bf16x4*)&P[(m * 64 + j * 16 + quad * 4) ^ ((m & 7) << 3)] = u;
        }
    }
    __syncthreads();

    // ---- O^T = (V^T)(P) via swapped MFMA: o[i][tj][r] = O[m=i*16+col][d=tj*16+quad*4+r]
    float4_t o[4][2] = {};
#pragma unroll
    for (int s2 = 0; s2 < 2; ++s2) {
        short8 pa[4], vb[2];
#pragma unroll
        for (int i = 0; i < 4; ++i) {
            int m = i * 16 + col;
            pa[i] = *(const short8*)&P[(m * 64 + s2 * 32 + quad * 8) ^ ((m & 7) << 3)];
        }
#pragma unroll
        for (int tj = 0; tj < 2; ++tj) {
            int d = tj * 16 + col;
            vb[tj] = *(const short8*)&Vt[(d * 64 + s2 * 32 + quad * 8) ^ ((d & 7) << 3)];
        }
        __builtin_amdgcn_s_setprio(1);
#pragma unroll
        for (int i = 0; i < 4; ++i)
#pragma unroll
            for (int tj = 0; tj < 2; ++tj)
                o[i][tj] = __builtin_amdgcn_mfma_f32_16x16x32_bf16(vb[tj], pa[i], o[i][tj], 0, 0, 0);
        __builtin_amdgcn_s_setprio(0);
    }

    // ---- store (bf16, (M,512) row-major feeds proj GEMM), bf16x4 vectorized ----
#pragma unroll
    for (int i = 0; i < 4; ++i) {
        int m = i * 16 + col;
        if (m < 49) {
            size_t ob = (size_t)(w * 49 + m) * 512 + hh * 32 + quad * 4;
#pragma unroll
            for (int tj = 0; tj < 2; ++tj) {
                bf16x4 u;
#pragma unroll
                for (int r = 0; r < 4; ++r) u[r] = f2bf(o[i][tj][r]);
                *(bf16x4*)&attn_out[ob + tj * 16] = u;
            }
        }
    }
}

// ---------------------------------------------------------------------------
extern "C" void kernel_launch(void* const* d_in, const int* in_sizes, int n_in,
                              void* d_out, int out_size, void* d_ws, size_t ws_size,
                              hipStream_t stream) {
    const float* x        = (const float*)d_in[0];
    const float* mask     = (const float*)d_in[1];
    const float* qkv_w    = (const float*)d_in[2];
    const float* qkv_b    = (const float*)d_in[3];
    const float* proj_w   = (const float*)d_in[4];
    const float* proj_b   = (const float*)d_in[5];
    const float* bias_tab = (const float*)d_in[6];
    const int*   rel_idx  = (const int*)d_in[7];
    float* out = (float*)d_out;

    char* ws = (char*)d_ws;
    size_t off = 0;
    auto carve = [&](size_t bytes) -> char* {
        char* p = ws + off;
        off += (bytes + 255) & ~(size_t)255;
        return p;
    };
    unsigned short* x_bf    = (unsigned short*)carve((size_t)51380224 * 2);   // 102.8 MB
    unsigned short* qkv_wT  = (unsigned short*)carve((size_t)786432 * 2);
    unsigned short* proj_wT = (unsigned short*)carve((size_t)262144 * 2);
    float*          biasP   = (float*)carve((size_t)50176 * 4);
    float*          maskP   = (float*)carve((size_t)200704 * 4);
    unsigned short* qkv_o   = (unsigned short*)carve((size_t)100352 * 1536 * 2); // 308.3 MB
    unsigned short* attn_o  = x_bf;  // x_bf dead after QKV GEMM; alias saves 103 MB

    cvt_x<<<25088, 256, 0, stream>>>((const float4_t*)x, x_bf, 6422528);
    prep<<<5076, 256, 0, stream>>>(qkv_w, proj_w, bias_tab, rel_idx, mask,
                                   qkv_wT, proj_wT, biasP, maskP);
    // qkv = x @ qkv_w + b, q-cols scaled by 32^-0.5, bf16 out
    gemm_bt<0><<<9408, 256, 0, stream>>>(x_bf, qkv_wT, (void*)qkv_o, qkv_b,
                                         100352, 1536, 512, 0.17677669529663687f);
    attn_win<<<32768, 64, 0, stream>>>(qkv_o, maskP, biasP, attn_o);
    // out = attn_o @ proj_w + proj_b, fp32 out
    gemm_bt<1><<<3136, 256, 0, stream>>>(attn_o, proj_wT, (void*)out, proj_b,
                                         100352, 512, 512, 1.0f);
}